// Round 5
// baseline (3114.482 us; speedup 1.0000x reference)
//
#include <hip/hip_runtime.h>
#include <stdint.h>

#define N_NODES 50000
#define N_EDGES 200000

typedef __bf16 bf16_t;
typedef bf16_t bf16x8 __attribute__((ext_vector_type(8)));
typedef float f32x4 __attribute__((ext_vector_type(4)));

__device__ __forceinline__ float bf2f(ushort h) {
  union { unsigned int u; float f; } c; c.u = ((unsigned int)h) << 16; return c.f;
}
__device__ __forceinline__ ushort f2bf(float f) {
  union { float f; unsigned int u; } c; c.f = f;
  unsigned int r = (c.u >> 16) & 1u;
  c.u += 0x7fffu + r;
  return (ushort)(c.u >> 16);
}
__device__ __forceinline__ float wave_sum(float v) {
#pragma unroll
  for (int m = 32; m > 0; m >>= 1) v += __shfl_xor(v, m, 64);
  return v;
}

// ---------------- input dtype detection + canonicalization ----------------
// f32-stored inputs read as ushort: low halves are uniform bits -> ~0.39%
// bf16-NaN patterns (~1900 in 1M). Genuine bf16 normal data: exactly 0.
__global__ void detect_k(const ushort* x, unsigned int* flag) {
  int i = blockIdx.x * 256 + threadIdx.x;  // 64 blocks
  unsigned int cnt = 0;
  for (int j = i; j < 1000000; j += 64 * 256) {
    ushort v = x[j];
    if (((v & 0x7F80u) == 0x7F80u) && (v & 0x7Fu)) cnt++;
  }
  if (cnt) atomicAdd(flag, cnt);
}

__global__ void cvt_in_k(const void* src, ushort* dst, int n, const unsigned int* flag) {
  int i = blockIdx.x * 256 + threadIdx.x;
  if (i >= n) return;
  if (*flag >= 2) dst[i] = f2bf(((const float*)src)[i]);
  else            dst[i] = ((const ushort*)src)[i];
}

// transpose + dtype-canonicalize weights: W [K][Nw] -> Bt [Nw][Kpad]
__global__ void transpose_k(const void* W, ushort* Bt, int K, int Kpad, int Nw,
                            const unsigned int* flag) {
  int k = blockIdx.x * 256 + threadIdx.x;
  int n = blockIdx.y;
  if (k >= Kpad) return;
  ushort v = 0;
  if (k < K) {
    if (*flag >= 2) v = f2bf(((const float*)W)[(size_t)k * Nw + n]);
    else            v = ((const ushort*)W)[(size_t)k * Nw + n];
  }
  Bt[(size_t)n * Kpad + k] = v;
}

// ---------------- GEMM ----------------
// MODE 0: plain bf16 A = E2, row stride K
// MODE 1: enc : [x[row](160) | x[col](160) | eattr(8) | 0-pad ->352]
// MODE 2: edge: [x[row]|lat[row] | x[col]|lat[col] | el[e](128)]  K=768
// MODE 3: msg : [x[col]|lat[col] | E2[e*e2s .. +64]]              K=384
// MODE 4: plain f32 A = Af, row stride K (converted to bf16 in staging)
struct GemmP {
  const ushort* X;     // canonical x [N,160]
  const ushort* L;     // nlat [N,160]
  const ushort* E2;    // per-edge operand
  const float*  Af;    // plain f32 A (mode 4)
  const int* row;
  const int* col;
  const ushort* Bt;    // [Nw][K] transposed weight
  const ushort* bias;  // [Nw] bf16
  ushort* outb;  long ob_stride;
  ushort* outb2; long ob2_stride;
  float*  outf;  long of_stride;
  long e2s;
  int M, K, Nw;
};

template <int MODE>
__device__ __forceinline__ uint4 load_a8(const GemmP& p, int e, int ri, int ci, int kg) {
  if (MODE == 0) {
    return *(const uint4*)(p.E2 + (size_t)e * p.K + kg);
  } else if (MODE == 1) {
    if (kg < 160)      return *(const uint4*)(p.X + (size_t)ri * 160 + kg);
    else if (kg < 320) return *(const uint4*)(p.X + (size_t)ci * 160 + (kg - 160));
    else if (kg < 328) return *(const uint4*)(p.E2 + (size_t)e * 8 + (kg - 320));
    uint4 z; z.x = z.y = z.z = z.w = 0u; return z;
  } else if (MODE == 2) {
    if (kg < 160)      return *(const uint4*)(p.X + (size_t)ri * 160 + kg);
    else if (kg < 320) return *(const uint4*)(p.L + (size_t)ri * 160 + (kg - 160));
    else if (kg < 480) return *(const uint4*)(p.X + (size_t)ci * 160 + (kg - 320));
    else if (kg < 640) return *(const uint4*)(p.L + (size_t)ci * 160 + (kg - 480));
    return *(const uint4*)(p.E2 + (size_t)e * 128 + (kg - 640));
  } else if (MODE == 3) {
    if (kg < 160)      return *(const uint4*)(p.X + (size_t)ci * 160 + kg);
    else if (kg < 320) return *(const uint4*)(p.L + (size_t)ci * 160 + (kg - 160));
    return *(const uint4*)(p.E2 + (size_t)e * p.e2s + (kg - 320));
  } else {  // MODE 4: f32 -> bf16
    const float* s = p.Af + (size_t)e * p.K + kg;
    f32x4 f0 = *(const f32x4*)s;
    f32x4 f1 = *(const f32x4*)(s + 4);
    union { ushort r[8]; uint4 u; } o;
    o.r[0] = f2bf(f0[0]); o.r[1] = f2bf(f0[1]); o.r[2] = f2bf(f0[2]); o.r[3] = f2bf(f0[3]);
    o.r[4] = f2bf(f1[0]); o.r[5] = f2bf(f1[1]); o.r[6] = f2bf(f1[2]); o.r[7] = f2bf(f1[3]);
    return o.u;
  }
}

template <int MODE, bool RELU>
__global__ __launch_bounds__(256) void gemm_k(GemmP p) {
  __shared__ __align__(16) ushort Asm[128 * 40];
  __shared__ __align__(16) ushort Bsm[64 * 40];
  const int t = threadIdx.x;
  const int w = t >> 6;
  const int l = t & 63;
  const int m0 = blockIdx.x * 128;
  const int n0 = blockIdx.y * 64;

  const int srow = t >> 1;
  const int skk = (t & 1) << 4;
  int e = m0 + srow;
  if (e >= p.M) e = p.M - 1;
  int ri = 0, ci = 0;
  if (MODE == 1 || MODE == 2 || MODE == 3) { ri = p.row[e]; ci = p.col[e]; }

  const int bn = t >> 2;
  const int bkk = (t & 3) << 3;
  const bool bok = (n0 + bn) < p.Nw;
  const ushort* BtRow = p.Bt + (size_t)(n0 + bn) * p.K;

  const int mq = l & 15;
  const int qd = l >> 4;

  f32x4 acc[2][4] = {};

  for (int k0 = 0; k0 < p.K; k0 += 32) {
    uint4 a0 = load_a8<MODE>(p, e, ri, ci, k0 + skk);
    uint4 a1 = load_a8<MODE>(p, e, ri, ci, k0 + skk + 8);
    uint4 b;
    if (bok) b = *(const uint4*)(BtRow + k0 + bkk);
    else { b.x = b.y = b.z = b.w = 0u; }
    *(uint4*)&Asm[srow * 40 + skk] = a0;
    *(uint4*)&Asm[srow * 40 + skk + 8] = a1;
    *(uint4*)&Bsm[bn * 40 + bkk] = b;
    __syncthreads();
    uint4 ra0 = *(const uint4*)&Asm[(w * 32 + mq) * 40 + qd * 8];
    uint4 ra1 = *(const uint4*)&Asm[(w * 32 + 16 + mq) * 40 + qd * 8];
    bf16x8 af0 = __builtin_bit_cast(bf16x8, ra0);
    bf16x8 af1 = __builtin_bit_cast(bf16x8, ra1);
#pragma unroll
    for (int nt = 0; nt < 4; nt++) {
      uint4 rb = *(const uint4*)&Bsm[(nt * 16 + mq) * 40 + qd * 8];
      bf16x8 bfv = __builtin_bit_cast(bf16x8, rb);
      acc[0][nt] = __builtin_amdgcn_mfma_f32_16x16x32_bf16(af0, bfv, acc[0][nt], 0, 0, 0);
      acc[1][nt] = __builtin_amdgcn_mfma_f32_16x16x32_bf16(af1, bfv, acc[1][nt], 0, 0, 0);
    }
    __syncthreads();
  }

#pragma unroll
  for (int mt = 0; mt < 2; mt++) {
#pragma unroll
    for (int nt = 0; nt < 4; nt++) {
      int c = n0 + nt * 16 + mq;
      if (c >= p.Nw) continue;
      float bv = bf2f(p.bias[c]);
#pragma unroll
      for (int i = 0; i < 4; i++) {
        int r = m0 + w * 32 + mt * 16 + qd * 4 + i;
        if (r >= p.M) continue;
        float v = acc[mt][nt][i] + bv;
        if (RELU) v = fmaxf(v, 0.0f);
        if (p.outb)  p.outb[(size_t)r * p.ob_stride + c] = f2bf(v);
        if (p.outb2) p.outb2[(size_t)r * p.ob2_stride + c] = f2bf(v);
        if (p.outf)  p.outf[(size_t)r * p.of_stride + c] = v;
      }
    }
  }
}

// ---------------- small kernels ----------------
__global__ void copy_u4_k(const uint4* s, uint4* d, int n) {
  int i = blockIdx.x * 256 + threadIdx.x;
  if (i < n) d[i] = s[i];
}

// attention: logits + exp + denominator (no max-shift; logits are O(1))
__global__ void att_k(const ushort* msg, const ushort* att, const int* row,
                      float* exb, float* den, int E) {
  int e = blockIdx.x * 4 + (threadIdx.x >> 6);
  int l = threadIdx.x & 63;
  if (e >= E) return;
  float s = 0.0f;
#pragma unroll
  for (int j = 0; j < 4; j++) {
    int c = l + (j << 6);
    s += bf2f(msg[(size_t)e * 256 + c]) * bf2f(att[c]);
  }
  s = wave_sum(s);
  if (l == 0) {
    float lg = (s > 0.0f) ? s : 0.2f * s;
    lg = fminf(fmaxf(lg, -60.0f), 60.0f);  // never active; inf-proofing
    float ex = __expf(lg);
    exb[e] = ex;
    atomicAdd(&den[row[e]], ex);
  }
}

__global__ void scatter_k(const ushort* msg, const float* exb, const float* den,
                          const int* row, float* agg, int E) {
  int e = blockIdx.x * 4 + (threadIdx.x >> 6);
  int l = threadIdx.x & 63;
  if (e >= E) return;
  int r = row[e];
  float alpha = exb[e] / (den[r] + 1e-16f);
#pragma unroll
  for (int j = 0; j < 4; j++) {
    int c = l + (j << 6);
    atomicAdd(&agg[(size_t)r * 256 + c], alpha * bf2f(msg[(size_t)e * 256 + c]));
  }
}

__global__ void ln_node_k(const ushort* x, const float* nn, const ushort* g,
                          const ushort* b, ushort* nlat) {
  int n = blockIdx.x * 4 + (threadIdx.x >> 6);
  int l = threadIdx.x & 63;
  if (n >= N_NODES) return;
  size_t bx = (size_t)n * 160;
  float v0 = bf2f(x[bx + l]) + nn[bx + l];
  float v1 = bf2f(x[bx + 64 + l]) + nn[bx + 64 + l];
  float v2 = (l < 32) ? (bf2f(x[bx + 128 + l]) + nn[bx + 128 + l]) : 0.0f;
  float mu = wave_sum(v0 + v1 + v2) * (1.0f / 160.0f);
  float d0 = v0 - mu, d1 = v1 - mu;
  float d2 = (l < 32) ? (v2 - mu) : 0.0f;
  float var = wave_sum(d0 * d0 + d1 * d1 + d2 * d2) * (1.0f / 160.0f);
  float inv = rsqrtf(var + 1e-5f);
  nlat[bx + l]      = f2bf(d0 * inv * bf2f(g[l])      + bf2f(b[l]));
  nlat[bx + 64 + l] = f2bf(d1 * inv * bf2f(g[64 + l]) + bf2f(b[64 + l]));
  if (l < 32)
    nlat[bx + 128 + l] = f2bf(d2 * inv * bf2f(g[128 + l]) + bf2f(b[128 + l]));
}

// el layout: [e][0:64] = init_edge, [e][64:128] = new_edge (pre-LN) -> LN'd in place
__global__ void ln_edge_k(const ushort* g, const ushort* b, ushort* el) {
  int e = blockIdx.x * 4 + (threadIdx.x >> 6);
  int l = threadIdx.x & 63;
  if (e >= N_EDGES) return;
  float v = bf2f(el[(size_t)e * 128 + l]) + bf2f(el[(size_t)e * 128 + 64 + l]);
  float mu = wave_sum(v) * (1.0f / 64.0f);
  float d = v - mu;
  float var = wave_sum(d * d) * (1.0f / 64.0f);
  float inv = rsqrtf(var + 1e-5f);
  el[(size_t)e * 128 + 64 + l] = f2bf(d * inv * bf2f(g[l]) + bf2f(b[l]));
}

// ---------------- output (dtype follows detected input dtype) ----------------
__global__ void out_node_k(const ushort* nlat, void* out, const unsigned int* flag) {
  int i = blockIdx.x * 256 + threadIdx.x;
  if (i >= N_NODES * 160) return;
  if (*flag >= 2) ((float*)out)[i] = bf2f(nlat[i]);
  else            ((ushort*)out)[i] = nlat[i];
}
__global__ void out_edge_k(const ushort* el, void* out, const unsigned int* flag) {
  int i = blockIdx.x * 256 + threadIdx.x;
  if (i >= N_EDGES * 64) return;
  int e = i >> 6, c = i & 63;
  ushort v = el[(size_t)e * 128 + 64 + c];
  size_t o = (size_t)N_NODES * 160 + i;
  if (*flag >= 2) ((float*)out)[o] = bf2f(v);
  else            ((ushort*)out)[o] = v;
}

// ---------------- host ----------------
extern "C" void kernel_launch(void* const* d_in, const int* in_sizes, int n_in,
                              void* d_out, int out_size, void* d_ws, size_t ws_size,
                              hipStream_t stream) {
  const void* x_r     = d_in[0];
  const void* eattr_r = d_in[1];
  const void* encW1   = d_in[2];
  const void* encb1_r = d_in[3];
  const void* encW2   = d_in[4];
  const void* encb2_r = d_in[5];
  const void* eW1     = d_in[6];
  const void* eb1_r   = d_in[7];
  const void* eW2     = d_in[8];
  const void* eb2_r   = d_in[9];
  const void* mW1     = d_in[10];
  const void* mb1_r   = d_in[11];
  const void* attv_r  = d_in[12];
  const void* nW1     = d_in[13];
  const void* nb1_r   = d_in[14];
  const void* lnng_r  = d_in[15];
  const void* lnnb_r  = d_in[16];
  const void* lneg_r  = d_in[17];
  const void* lneb_r  = d_in[18];
  const int* erow = (const int*)d_in[19];
  const int* ecol = (const int*)d_in[20];
  (void)in_sizes; (void)n_in;

  char* ws = (char*)d_ws;
  size_t off = 0;
  auto alloc = [&](size_t bytes) -> void* {
    void* p = ws + off;
    off = (off + bytes + 511) & ~(size_t)511;
    return p;
  };
  ushort* hm   = (ushort*)alloc((size_t)N_EDGES * 256 * 2);  // h / msg / nnf(f32) alias
  ushort* el   = (ushort*)alloc((size_t)N_EDGES * 128 * 2);
  float*  agg  = (float*)alloc((size_t)N_NODES * 256 * 4);   // eac aliases its head
  float*  den  = (float*)alloc((size_t)N_NODES * 4);
  ushort* xc   = (ushort*)alloc((size_t)N_NODES * 160 * 2);
  ushort* nlat = (ushort*)alloc((size_t)N_NODES * 160 * 2);
  float*  exb  = (float*)alloc((size_t)N_EDGES * 4);
  ushort* BtE1 = (ushort*)alloc((size_t)128 * 352 * 2);
  ushort* BtE2 = (ushort*)alloc((size_t)64 * 128 * 2);
  ushort* Bte1 = (ushort*)alloc((size_t)256 * 768 * 2);
  ushort* Bte2 = (ushort*)alloc((size_t)64 * 256 * 2);
  ushort* Btm1 = (ushort*)alloc((size_t)256 * 384 * 2);
  ushort* Btn1 = (ushort*)alloc((size_t)160 * 256 * 2);
  ushort* pool = (ushort*)alloc((size_t)2048 * 2);
  unsigned int* flag = (unsigned int*)alloc(64);
  ushort* msg = hm;
  float*  nnf = (float*)hm;
  ushort* eac = (ushort*)agg;  // canonical eattr, dead before first agg memset

  // small-vector canonical slots
  ushort* encb1c = pool;        ushort* encb2c = pool + 128;
  ushort* eb1c   = pool + 192;  ushort* eb2c   = pool + 448;
  ushort* mb1c   = pool + 512;  ushort* attvc  = pool + 768;
  ushort* nb1c   = pool + 1024; ushort* lnngc  = pool + 1184;
  ushort* lnnbc  = pool + 1344; ushort* lnegc  = pool + 1504;
  ushort* lnebc  = pool + 1568;

  if (off > ws_size) {  // diagnostic: clean absmax fail (4.94), no fault
    hipMemsetAsync(d_out, 0, (size_t)out_size * 2, stream);
    return;
  }

  hipMemsetAsync(ws, 0, off, stream);  // read-before-write => 0.0, never poison

  detect_k<<<64, 256, 0, stream>>>((const ushort*)x_r, flag);

  // canonicalize inputs to bf16
  cvt_in_k<<<(N_NODES * 160 + 255) / 256, 256, 0, stream>>>(x_r, xc, N_NODES * 160, flag);
  cvt_in_k<<<(N_EDGES * 8 + 255) / 256, 256, 0, stream>>>(eattr_r, eac, N_EDGES * 8, flag);
  cvt_in_k<<<1, 256, 0, stream>>>(encb1_r, encb1c, 128, flag);
  cvt_in_k<<<1, 256, 0, stream>>>(encb2_r, encb2c, 64, flag);
  cvt_in_k<<<1, 256, 0, stream>>>(eb1_r, eb1c, 256, flag);
  cvt_in_k<<<1, 256, 0, stream>>>(eb2_r, eb2c, 64, flag);
  cvt_in_k<<<1, 256, 0, stream>>>(mb1_r, mb1c, 256, flag);
  cvt_in_k<<<1, 256, 0, stream>>>(attv_r, attvc, 256, flag);
  cvt_in_k<<<1, 256, 0, stream>>>(nb1_r, nb1c, 160, flag);
  cvt_in_k<<<1, 256, 0, stream>>>(lnng_r, lnngc, 160, flag);
  cvt_in_k<<<1, 256, 0, stream>>>(lnnb_r, lnnbc, 160, flag);
  cvt_in_k<<<1, 256, 0, stream>>>(lneg_r, lnegc, 64, flag);
  cvt_in_k<<<1, 256, 0, stream>>>(lneb_r, lnebc, 64, flag);

  transpose_k<<<dim3(2, 128), 256, 0, stream>>>(encW1, BtE1, 328, 352, 128, flag);
  transpose_k<<<dim3(1, 64), 256, 0, stream>>>(encW2, BtE2, 128, 128, 64, flag);
  transpose_k<<<dim3(3, 256), 256, 0, stream>>>(eW1, Bte1, 768, 768, 256, flag);
  transpose_k<<<dim3(1, 64), 256, 0, stream>>>(eW2, Bte2, 256, 256, 64, flag);
  transpose_k<<<dim3(2, 256), 256, 0, stream>>>(mW1, Btm1, 384, 384, 256, flag);
  transpose_k<<<dim3(1, 160), 256, 0, stream>>>(nW1, Btn1, 256, 256, 160, flag);

  // nlat = x (iteration 0 latent)
  copy_u4_k<<<(N_NODES * 160 / 8 + 255) / 256, 256, 0, stream>>>(
      (const uint4*)xc, (uint4*)nlat, N_NODES * 160 / 8);

  const int gE = (N_EDGES + 127) / 128;  // 1563
  const int gN = (N_NODES + 127) / 128;  // 391
  const size_t clr_bytes = (size_t)((char*)(den + N_NODES) - (char*)agg);

  {  // encoder GEMM1: [E,352] @ [352,128] relu -> hm (stride 128)
    GemmP p{};
    p.X = xc; p.E2 = eac; p.row = erow; p.col = ecol;
    p.Bt = BtE1; p.bias = encb1c;
    p.outb = hm; p.ob_stride = 128;
    p.M = N_EDGES; p.K = 352; p.Nw = 128;
    gemm_k<1, true><<<dim3(gE, 2), 256, 0, stream>>>(p);
  }
  {  // encoder GEMM2: hm @ [128,64] -> el[:,0:64] and el[:,64:128]
    GemmP p{};
    p.E2 = hm; p.Bt = BtE2; p.bias = encb2c;
    p.outb = el; p.ob_stride = 128;
    p.outb2 = el + 64; p.ob2_stride = 128;
    p.M = N_EDGES; p.K = 128; p.Nw = 64;
    gemm_k<0, false><<<dim3(gE, 1), 256, 0, stream>>>(p);
  }

  for (int it = 0; it < 3; it++) {
    {  // edge GEMM1: [E,768] @ [768,256] relu -> hm
      GemmP p{};
      p.X = xc; p.L = nlat; p.E2 = el; p.row = erow; p.col = ecol;
      p.Bt = Bte1; p.bias = eb1c;
      p.outb = hm; p.ob_stride = 256;
      p.M = N_EDGES; p.K = 768; p.Nw = 256;
      gemm_k<2, true><<<dim3(gE, 4), 256, 0, stream>>>(p);
    }
    {  // edge GEMM2: hm @ [256,64] -> new_edge into el upper half (pre-LN)
      GemmP p{};
      p.E2 = hm; p.Bt = Bte2; p.bias = eb2c;
      p.outb = el + 64; p.ob_stride = 128;
      p.M = N_EDGES; p.K = 256; p.Nw = 64;
      gemm_k<0, false><<<dim3(gE, 1), 256, 0, stream>>>(p);
    }
    {  // msg GEMM: [nl[col](320) | new_edge(64)] @ [384,256] relu -> msg (=hm)
      GemmP p{};
      p.X = xc; p.L = nlat; p.E2 = el + 64; p.e2s = 128;
      p.row = erow; p.col = ecol;
      p.Bt = Btm1; p.bias = mb1c;
      p.outb = msg; p.ob_stride = 256;
      p.M = N_EDGES; p.K = 384; p.Nw = 256;
      gemm_k<3, true><<<dim3(gE, 4), 256, 0, stream>>>(p);
    }
    // edge LN in place (after msg GEMM consumed pre-LN new_edge)
    ln_edge_k<<<N_EDGES / 4, 256, 0, stream>>>(lnegc, lnebc, el);
    hipMemsetAsync(agg, 0, clr_bytes, stream);  // agg=0, den=0
    att_k<<<N_EDGES / 4, 256, 0, stream>>>(msg, attvc, erow, exb, den, N_EDGES);
    scatter_k<<<N_EDGES / 4, 256, 0, stream>>>(msg, exb, den, erow, agg, N_EDGES);
    {  // node GEMM: agg(f32) [N,256] @ [256,160] -> nnf (f32, aliases hm)
      GemmP p{};
      p.Af = agg; p.Bt = Btn1; p.bias = nb1c;
      p.outf = nnf; p.of_stride = 160;
      p.M = N_NODES; p.K = 256; p.Nw = 160;
      gemm_k<4, false><<<dim3(gN, 3), 256, 0, stream>>>(p);
    }
    ln_node_k<<<(N_NODES + 3) / 4, 256, 0, stream>>>(xc, nnf, lnngc, lnnbc, nlat);
  }

  // outputs: node_lat [N,160] then edge_lat [E,64]; dtype follows input dtype
  out_node_k<<<(N_NODES * 160 + 255) / 256, 256, 0, stream>>>(nlat, d_out, flag);
  out_edge_k<<<(N_EDGES * 64 + 255) / 256, 256, 0, stream>>>(el, d_out, flag);
  (void)out_size;
}

// Round 6
// 2996.989 us; speedup vs baseline: 1.0392x; 1.0392x over previous
//
#include <hip/hip_runtime.h>
#include <stdint.h>

#define N_NODES 50000
#define N_EDGES 200000

typedef __bf16 bf16_t;
typedef bf16_t bf16x8 __attribute__((ext_vector_type(8)));
typedef float f32x4 __attribute__((ext_vector_type(4)));

__device__ __forceinline__ float bf2f(ushort h) {
  union { unsigned int u; float f; } c; c.u = ((unsigned int)h) << 16; return c.f;
}
__device__ __forceinline__ ushort f2bf(float f) {
  union { float f; unsigned int u; } c; c.f = f;
  unsigned int r = (c.u >> 16) & 1u;
  c.u += 0x7fffu + r;
  return (ushort)(c.u >> 16);
}
__device__ __forceinline__ float wave_sum(float v) {
#pragma unroll
  for (int m = 32; m > 0; m >>= 1) v += __shfl_xor(v, m, 64);
  return v;
}

// ---------------- input dtype detection + canonicalization ----------------
__global__ void detect_k(const ushort* x, unsigned int* flag) {
  int i = blockIdx.x * 256 + threadIdx.x;
  unsigned int cnt = 0;
  for (int j = i; j < 1000000; j += 64 * 256) {
    ushort v = x[j];
    if (((v & 0x7F80u) == 0x7F80u) && (v & 0x7Fu)) cnt++;
  }
  if (cnt) atomicAdd(flag, cnt);
}

__global__ void cvt_in_k(const void* src, ushort* dst, int n, const unsigned int* flag) {
  int i = blockIdx.x * 256 + threadIdx.x;
  if (i >= n) return;
  if (*flag >= 2) dst[i] = f2bf(((const float*)src)[i]);
  else            dst[i] = ((const ushort*)src)[i];
}

__global__ void transpose_k(const void* W, ushort* Bt, int K, int Kpad, int Nw,
                            const unsigned int* flag) {
  int k = blockIdx.x * 256 + threadIdx.x;
  int n = blockIdx.y;
  if (k >= Kpad) return;
  ushort v = 0;
  if (k < K) {
    if (*flag >= 2) v = f2bf(((const float*)W)[(size_t)k * Nw + n]);
    else            v = ((const ushort*)W)[(size_t)k * Nw + n];
  }
  Bt[(size_t)n * Kpad + k] = v;
}

// ---------------- GEMM ----------------
// MODE 0: plain bf16 A = E2, row stride K
// MODE 1: enc : [x[row](160) | x[col](160) | eattr(8) | 0-pad ->384]
// MODE 2: edge: [x[row]|lat[row] | x[col]|lat[col] | el[e](128)]  K=768
// MODE 3: msg : [x[col]|lat[col] | E2[e*e2s .. +64]]              K=384
// MODE 4: plain f32 A = Af, row stride K (converted to bf16 in staging)
struct GemmP {
  const ushort* X;
  const ushort* L;
  const ushort* E2;
  const float*  Af;
  const int* row;
  const int* col;
  const ushort* Bt;    // [Nw][K] transposed weight
  const ushort* bias;  // [Nw] bf16
  ushort* outb;  long ob_stride;
  ushort* outb2; long ob2_stride;
  float*  outf;  long of_stride;
  long e2s;
  int M, K, Nw;
};

template <int MODE>
__device__ __forceinline__ uint4 load_a8(const GemmP& p, int e, int ri, int ci, int kg) {
  if (MODE == 0) {
    return *(const uint4*)(p.E2 + (size_t)e * p.K + kg);
  } else if (MODE == 1) {
    if (kg < 160)      return *(const uint4*)(p.X + (size_t)ri * 160 + kg);
    else if (kg < 320) return *(const uint4*)(p.X + (size_t)ci * 160 + (kg - 160));
    else if (kg < 328) return *(const uint4*)(p.E2 + (size_t)e * 8 + (kg - 320));
    uint4 z; z.x = z.y = z.z = z.w = 0u; return z;
  } else if (MODE == 2) {
    if (kg < 160)      return *(const uint4*)(p.X + (size_t)ri * 160 + kg);
    else if (kg < 320) return *(const uint4*)(p.L + (size_t)ri * 160 + (kg - 160));
    else if (kg < 480) return *(const uint4*)(p.X + (size_t)ci * 160 + (kg - 320));
    else if (kg < 640) return *(const uint4*)(p.L + (size_t)ci * 160 + (kg - 480));
    return *(const uint4*)(p.E2 + (size_t)e * 128 + (kg - 640));
  } else if (MODE == 3) {
    if (kg < 160)      return *(const uint4*)(p.X + (size_t)ci * 160 + kg);
    else if (kg < 320) return *(const uint4*)(p.L + (size_t)ci * 160 + (kg - 160));
    return *(const uint4*)(p.E2 + (size_t)e * p.e2s + (kg - 320));
  } else {
    const float* s = p.Af + (size_t)e * p.K + kg;
    f32x4 f0 = *(const f32x4*)s;
    f32x4 f1 = *(const f32x4*)(s + 4);
    union { ushort r[8]; uint4 u; } o;
    o.r[0] = f2bf(f0[0]); o.r[1] = f2bf(f0[1]); o.r[2] = f2bf(f0[2]); o.r[3] = f2bf(f0[3]);
    o.r[4] = f2bf(f1[0]); o.r[5] = f2bf(f1[1]); o.r[6] = f2bf(f1[2]); o.r[7] = f2bf(f1[3]);
    return o.u;
  }
}

// BM=128, BK=64, BN=NT*16. Register-prefetch pipeline: tile k+1's global
// loads issue before tile k's MFMAs; vmcnt drain lands after compute.
template <int MODE, bool RELU, int NT>
__global__ __launch_bounds__(256) void gemm_k(GemmP p) {
  constexpr int BR = NT / 2;  // B 16B-chunks per thread per tile
  __shared__ __align__(16) ushort Asm[128 * 72];
  __shared__ __align__(16) ushort Bsm[NT * 16 * 72];
  const int t = threadIdx.x;
  const int w = t >> 6;
  const int l = t & 63;
  const int m0 = blockIdx.x * 128;
  const int n0 = blockIdx.y * (NT * 16);

  // A staging: 2 threads/row, each 64B (4x16B) contiguous
  const int srow = t >> 1;
  const int sph = (t & 1) << 5;  // elem phase 0/32
  int e = m0 + srow;
  if (e >= p.M) e = p.M - 1;
  int ri = 0, ci = 0;
  if (MODE == 1 || MODE == 2 || MODE == 3) { ri = p.row[e]; ci = p.col[e]; }

  // B staging: flat chunk id -> (row, k8)
  int bn_[BR], bk_[BR];
#pragma unroll
  for (int j = 0; j < BR; j++) {
    int cid = j * 256 + t;
    bn_[j] = cid >> 3;
    bk_[j] = (cid & 7) << 3;
  }

  const int mq = l & 15;
  const int qd = l >> 4;

  uint4 ar[4];
  uint4 br[BR];
  auto load_tile = [&](int k0) {
#pragma unroll
    for (int j = 0; j < 4; j++)
      ar[j] = load_a8<MODE>(p, e, ri, ci, k0 + sph + j * 8);
#pragma unroll
    for (int j = 0; j < BR; j++)
      br[j] = *(const uint4*)(p.Bt + (size_t)(n0 + bn_[j]) * p.K + k0 + bk_[j]);
  };

  f32x4 acc[2][NT] = {};

  load_tile(0);
  const int kiters = p.K >> 6;
  for (int kt = 0; kt < kiters; kt++) {
    __syncthreads();
#pragma unroll
    for (int j = 0; j < 4; j++)
      *(uint4*)&Asm[srow * 72 + sph + j * 8] = ar[j];
#pragma unroll
    for (int j = 0; j < BR; j++)
      *(uint4*)&Bsm[bn_[j] * 72 + bk_[j]] = br[j];
    if (kt + 1 < kiters) load_tile((kt + 1) << 6);
    __syncthreads();
#pragma unroll
    for (int ph = 0; ph < 2; ph++) {
      uint4 ra0 = *(const uint4*)&Asm[(w * 32 + mq) * 72 + ph * 32 + qd * 8];
      uint4 ra1 = *(const uint4*)&Asm[(w * 32 + 16 + mq) * 72 + ph * 32 + qd * 8];
      bf16x8 af0 = __builtin_bit_cast(bf16x8, ra0);
      bf16x8 af1 = __builtin_bit_cast(bf16x8, ra1);
#pragma unroll
      for (int nt = 0; nt < NT; nt++) {
        uint4 rb = *(const uint4*)&Bsm[(nt * 16 + mq) * 72 + ph * 32 + qd * 8];
        bf16x8 bfv = __builtin_bit_cast(bf16x8, rb);
        acc[0][nt] = __builtin_amdgcn_mfma_f32_16x16x32_bf16(af0, bfv, acc[0][nt], 0, 0, 0);
        acc[1][nt] = __builtin_amdgcn_mfma_f32_16x16x32_bf16(af1, bfv, acc[1][nt], 0, 0, 0);
      }
    }
  }

#pragma unroll
  for (int mt = 0; mt < 2; mt++) {
#pragma unroll
    for (int nt = 0; nt < NT; nt++) {
      int c = n0 + nt * 16 + mq;  // always < Nw (gridy exact)
      float bv = bf2f(p.bias[c]);
#pragma unroll
      for (int i = 0; i < 4; i++) {
        int r = m0 + w * 32 + mt * 16 + qd * 4 + i;
        if (r >= p.M) continue;
        float v = acc[mt][nt][i] + bv;
        if (RELU) v = fmaxf(v, 0.0f);
        if (p.outb)  p.outb[(size_t)r * p.ob_stride + c] = f2bf(v);
        if (p.outb2) p.outb2[(size_t)r * p.ob2_stride + c] = f2bf(v);
        if (p.outf)  p.outf[(size_t)r * p.of_stride + c] = v;
      }
    }
  }
}

// ---------------- small kernels ----------------
__global__ void copy_u4_k(const uint4* s, uint4* d, int n) {
  int i = blockIdx.x * 256 + threadIdx.x;
  if (i < n) d[i] = s[i];
}

__global__ void att_k(const ushort* msg, const ushort* att, const int* row,
                      float* exb, float* den, int E) {
  int e = blockIdx.x * 4 + (threadIdx.x >> 6);
  int l = threadIdx.x & 63;
  if (e >= E) return;
  float s = 0.0f;
#pragma unroll
  for (int j = 0; j < 4; j++) {
    int c = l + (j << 6);
    s += bf2f(msg[(size_t)e * 256 + c]) * bf2f(att[c]);
  }
  s = wave_sum(s);
  if (l == 0) {
    float lg = (s > 0.0f) ? s : 0.2f * s;
    lg = fminf(fmaxf(lg, -60.0f), 60.0f);
    float ex = __expf(lg);
    exb[e] = ex;
    atomicAdd(&den[row[e]], ex);
  }
}

__global__ void scatter_k(const ushort* msg, const float* exb, const float* den,
                          const int* row, float* agg, int E) {
  int e = blockIdx.x * 4 + (threadIdx.x >> 6);
  int l = threadIdx.x & 63;
  if (e >= E) return;
  int r = row[e];
  float alpha = exb[e] / (den[r] + 1e-16f);
#pragma unroll
  for (int j = 0; j < 4; j++) {
    int c = l + (j << 6);
    atomicAdd(&agg[(size_t)r * 256 + c], alpha * bf2f(msg[(size_t)e * 256 + c]));
  }
}

__global__ void ln_node_k(const ushort* x, const float* nn, const ushort* g,
                          const ushort* b, ushort* nlat) {
  int n = blockIdx.x * 4 + (threadIdx.x >> 6);
  int l = threadIdx.x & 63;
  if (n >= N_NODES) return;
  size_t bx = (size_t)n * 160;
  float v0 = bf2f(x[bx + l]) + nn[bx + l];
  float v1 = bf2f(x[bx + 64 + l]) + nn[bx + 64 + l];
  float v2 = (l < 32) ? (bf2f(x[bx + 128 + l]) + nn[bx + 128 + l]) : 0.0f;
  float mu = wave_sum(v0 + v1 + v2) * (1.0f / 160.0f);
  float d0 = v0 - mu, d1 = v1 - mu;
  float d2 = (l < 32) ? (v2 - mu) : 0.0f;
  float var = wave_sum(d0 * d0 + d1 * d1 + d2 * d2) * (1.0f / 160.0f);
  float inv = rsqrtf(var + 1e-5f);
  nlat[bx + l]      = f2bf(d0 * inv * bf2f(g[l])      + bf2f(b[l]));
  nlat[bx + 64 + l] = f2bf(d1 * inv * bf2f(g[64 + l]) + bf2f(b[64 + l]));
  if (l < 32)
    nlat[bx + 128 + l] = f2bf(d2 * inv * bf2f(g[128 + l]) + bf2f(b[128 + l]));
}

__global__ void ln_edge_k(const ushort* g, const ushort* b, ushort* el) {
  int e = blockIdx.x * 4 + (threadIdx.x >> 6);
  int l = threadIdx.x & 63;
  if (e >= N_EDGES) return;
  float v = bf2f(el[(size_t)e * 128 + l]) + bf2f(el[(size_t)e * 128 + 64 + l]);
  float mu = wave_sum(v) * (1.0f / 64.0f);
  float d = v - mu;
  float var = wave_sum(d * d) * (1.0f / 64.0f);
  float inv = rsqrtf(var + 1e-5f);
  el[(size_t)e * 128 + 64 + l] = f2bf(d * inv * bf2f(g[l]) + bf2f(b[l]));
}

__global__ void out_node_k(const ushort* nlat, void* out, const unsigned int* flag) {
  int i = blockIdx.x * 256 + threadIdx.x;
  if (i >= N_NODES * 160) return;
  if (*flag >= 2) ((float*)out)[i] = bf2f(nlat[i]);
  else            ((ushort*)out)[i] = nlat[i];
}
__global__ void out_edge_k(const ushort* el, void* out, const unsigned int* flag) {
  int i = blockIdx.x * 256 + threadIdx.x;
  if (i >= N_EDGES * 64) return;
  int e = i >> 6, c = i & 63;
  ushort v = el[(size_t)e * 128 + 64 + c];
  size_t o = (size_t)N_NODES * 160 + i;
  if (*flag >= 2) ((float*)out)[o] = bf2f(v);
  else            ((ushort*)out)[o] = v;
}

// ---------------- host ----------------
extern "C" void kernel_launch(void* const* d_in, const int* in_sizes, int n_in,
                              void* d_out, int out_size, void* d_ws, size_t ws_size,
                              hipStream_t stream) {
  const void* x_r     = d_in[0];
  const void* eattr_r = d_in[1];
  const void* encW1   = d_in[2];
  const void* encb1_r = d_in[3];
  const void* encW2   = d_in[4];
  const void* encb2_r = d_in[5];
  const void* eW1     = d_in[6];
  const void* eb1_r   = d_in[7];
  const void* eW2     = d_in[8];
  const void* eb2_r   = d_in[9];
  const void* mW1     = d_in[10];
  const void* mb1_r   = d_in[11];
  const void* attv_r  = d_in[12];
  const void* nW1     = d_in[13];
  const void* nb1_r   = d_in[14];
  const void* lnng_r  = d_in[15];
  const void* lnnb_r  = d_in[16];
  const void* lneg_r  = d_in[17];
  const void* lneb_r  = d_in[18];
  const int* erow = (const int*)d_in[19];
  const int* ecol = (const int*)d_in[20];
  (void)in_sizes; (void)n_in;

  char* ws = (char*)d_ws;
  size_t off = 0;
  auto alloc = [&](size_t bytes) -> void* {
    void* p = ws + off;
    off = (off + bytes + 511) & ~(size_t)511;
    return p;
  };
  ushort* hm   = (ushort*)alloc((size_t)N_EDGES * 256 * 2);  // h / msg / nnf(f32) alias
  ushort* el   = (ushort*)alloc((size_t)N_EDGES * 128 * 2);
  float*  agg  = (float*)alloc((size_t)N_NODES * 256 * 4);   // eac aliases its head
  float*  den  = (float*)alloc((size_t)N_NODES * 4);
  ushort* xc   = (ushort*)alloc((size_t)N_NODES * 160 * 2);
  ushort* nlat = (ushort*)alloc((size_t)N_NODES * 160 * 2);
  float*  exb  = (float*)alloc((size_t)N_EDGES * 4);
  ushort* BtE1 = (ushort*)alloc((size_t)128 * 384 * 2);
  ushort* BtE2 = (ushort*)alloc((size_t)64 * 128 * 2);
  ushort* Bte1 = (ushort*)alloc((size_t)256 * 768 * 2);
  ushort* Bte2 = (ushort*)alloc((size_t)64 * 256 * 2);
  ushort* Btm1 = (ushort*)alloc((size_t)256 * 384 * 2);
  ushort* Btn1 = (ushort*)alloc((size_t)160 * 256 * 2);
  ushort* pool = (ushort*)alloc((size_t)2048 * 2);
  unsigned int* flag = (unsigned int*)alloc(64);
  ushort* msg = hm;
  float*  nnf = (float*)hm;
  ushort* eac = (ushort*)agg;

  ushort* encb1c = pool;        ushort* encb2c = pool + 128;
  ushort* eb1c   = pool + 192;  ushort* eb2c   = pool + 448;
  ushort* mb1c   = pool + 512;  ushort* attvc  = pool + 768;
  ushort* nb1c   = pool + 1024; ushort* lnngc  = pool + 1184;
  ushort* lnnbc  = pool + 1344; ushort* lnegc  = pool + 1504;
  ushort* lnebc  = pool + 1568;

  if (off > ws_size) {
    hipMemsetAsync(d_out, 0, (size_t)out_size * 2, stream);
    return;
  }

  hipMemsetAsync(flag, 0, 64, stream);

  detect_k<<<64, 256, 0, stream>>>((const ushort*)x_r, flag);

  cvt_in_k<<<(N_NODES * 160 + 255) / 256, 256, 0, stream>>>(x_r, xc, N_NODES * 160, flag);
  cvt_in_k<<<(N_EDGES * 8 + 255) / 256, 256, 0, stream>>>(eattr_r, eac, N_EDGES * 8, flag);
  cvt_in_k<<<1, 256, 0, stream>>>(encb1_r, encb1c, 128, flag);
  cvt_in_k<<<1, 256, 0, stream>>>(encb2_r, encb2c, 64, flag);
  cvt_in_k<<<1, 256, 0, stream>>>(eb1_r, eb1c, 256, flag);
  cvt_in_k<<<1, 256, 0, stream>>>(eb2_r, eb2c, 64, flag);
  cvt_in_k<<<1, 256, 0, stream>>>(mb1_r, mb1c, 256, flag);
  cvt_in_k<<<1, 256, 0, stream>>>(attv_r, attvc, 256, flag);
  cvt_in_k<<<1, 256, 0, stream>>>(nb1_r, nb1c, 160, flag);
  cvt_in_k<<<1, 256, 0, stream>>>(lnng_r, lnngc, 160, flag);
  cvt_in_k<<<1, 256, 0, stream>>>(lnnb_r, lnnbc, 160, flag);
  cvt_in_k<<<1, 256, 0, stream>>>(lneg_r, lnegc, 64, flag);
  cvt_in_k<<<1, 256, 0, stream>>>(lneb_r, lnebc, 64, flag);

  transpose_k<<<dim3(2, 128), 256, 0, stream>>>(encW1, BtE1, 328, 384, 128, flag);
  transpose_k<<<dim3(1, 64), 256, 0, stream>>>(encW2, BtE2, 128, 128, 64, flag);
  transpose_k<<<dim3(3, 256), 256, 0, stream>>>(eW1, Bte1, 768, 768, 256, flag);
  transpose_k<<<dim3(1, 64), 256, 0, stream>>>(eW2, Bte2, 256, 256, 64, flag);
  transpose_k<<<dim3(2, 256), 256, 0, stream>>>(mW1, Btm1, 384, 384, 256, flag);
  transpose_k<<<dim3(1, 160), 256, 0, stream>>>(nW1, Btn1, 256, 256, 160, flag);

  copy_u4_k<<<(N_NODES * 160 / 8 + 255) / 256, 256, 0, stream>>>(
      (const uint4*)xc, (uint4*)nlat, N_NODES * 160 / 8);

  const int gE = (N_EDGES + 127) / 128;  // 1563
  const int gN = (N_NODES + 127) / 128;  // 391
  const size_t clr_bytes = (size_t)((char*)(den + N_NODES) - (char*)agg);

  {  // encoder GEMM1: [E,384pad] @ [384,128] relu -> hm (stride 128)
    GemmP p{};
    p.X = xc; p.E2 = eac; p.row = erow; p.col = ecol;
    p.Bt = BtE1; p.bias = encb1c;
    p.outb = hm; p.ob_stride = 128;
    p.M = N_EDGES; p.K = 384; p.Nw = 128;
    gemm_k<1, true, 8><<<dim3(gE, 1), 256, 0, stream>>>(p);
  }
  {  // encoder GEMM2: hm @ [128,64] -> el[:,0:64] and el[:,64:128]
    GemmP p{};
    p.E2 = hm; p.Bt = BtE2; p.bias = encb2c;
    p.outb = el; p.ob_stride = 128;
    p.outb2 = el + 64; p.ob2_stride = 128;
    p.M = N_EDGES; p.K = 128; p.Nw = 64;
    gemm_k<0, false, 4><<<dim3(gE, 1), 256, 0, stream>>>(p);
  }

  for (int it = 0; it < 3; it++) {
    {  // edge GEMM1: [E,768] @ [768,256] relu -> hm
      GemmP p{};
      p.X = xc; p.L = nlat; p.E2 = el; p.row = erow; p.col = ecol;
      p.Bt = Bte1; p.bias = eb1c;
      p.outb = hm; p.ob_stride = 256;
      p.M = N_EDGES; p.K = 768; p.Nw = 256;
      gemm_k<2, true, 8><<<dim3(gE, 2), 256, 0, stream>>>(p);
    }
    {  // edge GEMM2: hm @ [256,64] -> new_edge into el upper half (pre-LN)
      GemmP p{};
      p.E2 = hm; p.Bt = Bte2; p.bias = eb2c;
      p.outb = el + 64; p.ob_stride = 128;
      p.M = N_EDGES; p.K = 256; p.Nw = 64;
      gemm_k<0, false, 4><<<dim3(gE, 1), 256, 0, stream>>>(p);
    }
    {  // msg GEMM: [nl[col](320) | new_edge(64)] @ [384,256] relu -> msg (=hm)
      GemmP p{};
      p.X = xc; p.L = nlat; p.E2 = el + 64; p.e2s = 128;
      p.row = erow; p.col = ecol;
      p.Bt = Btm1; p.bias = mb1c;
      p.outb = msg; p.ob_stride = 256;
      p.M = N_EDGES; p.K = 384; p.Nw = 256;
      gemm_k<3, true, 8><<<dim3(gE, 2), 256, 0, stream>>>(p);
    }
    ln_edge_k<<<N_EDGES / 4, 256, 0, stream>>>(lnegc, lnebc, el);
    hipMemsetAsync(agg, 0, clr_bytes, stream);  // agg=0, den=0
    att_k<<<N_EDGES / 4, 256, 0, stream>>>(msg, attvc, erow, exb, den, N_EDGES);
    scatter_k<<<N_EDGES / 4, 256, 0, stream>>>(msg, exb, den, erow, agg, N_EDGES);
    {  // node GEMM: agg(f32) [N,256] @ [256,160] -> nnf (f32, aliases hm)
      GemmP p{};
      p.Af = agg; p.Bt = Btn1; p.bias = nb1c;
      p.outf = nnf; p.of_stride = 160;
      p.M = N_NODES; p.K = 256; p.Nw = 160;
      gemm_k<4, false, 10><<<dim3(gN, 1), 256, 0, stream>>>(p);
    }
    ln_node_k<<<(N_NODES + 3) / 4, 256, 0, stream>>>(xc, nnf, lnngc, lnnbc, nlat);
  }

  out_node_k<<<(N_NODES * 160 + 255) / 256, 256, 0, stream>>>(nlat, d_out, flag);
  out_edge_k<<<(N_EDGES * 64 + 255) / 256, 256, 0, stream>>>(el, d_out, flag);
  (void)out_size;
}